// Round 1
// baseline (383.892 us; speedup 1.0000x reference)
//
#include <hip/hip_runtime.h>
#include <math.h>

#define NPOS 32768      // 32*32*32
#define CCH  128
#define C3   384
#define CF   512
#define NHEADS 8
#define HD   16

// ---------------------------------------------------------------------------
// Generic tiled fp32 GEMM: out[M,Nout] = A * B^T + bias (+gelu) (+residual)
//   A: row-major (M,Kd) if !ATRANS, else stored (Kd,M) (i.e. A[k*M+m])
//   B: row-major (Nout,Kd)  (weight layout (out,in))
// Tile 64x64, BK=16, 256 threads, 4x4 per thread.
// ---------------------------------------------------------------------------
template<bool ATRANS, bool GELU, bool RES>
__global__ __launch_bounds__(256) void gemm_kernel(
    const float* __restrict__ A, const float* __restrict__ B,
    const float* __restrict__ bias, const float* __restrict__ res,
    float* __restrict__ out, int M, int Nout, int Kd)
{
    __shared__ float As[16][68];
    __shared__ float Bs[16][68];
    const int row0 = blockIdx.y * 64;
    const int col0 = blockIdx.x * 64;
    const int tid = threadIdx.x;
    const int tx = tid & 15;       // 0..15 -> output col group
    const int ty = tid >> 4;       // 0..15 -> output row group

    float acc[4][4] = {};

    for (int kt = 0; kt < Kd; kt += 16) {
        // ---- stage A tile: As[k][m]
        if (ATRANS) {
            const int k  = tid >> 4;          // 0..15
            const int m0 = (tid & 15) * 4;    // 0..60
            const float4 av = *(const float4*)&A[(size_t)(kt + k) * M + row0 + m0];
            As[k][m0 + 0] = av.x; As[k][m0 + 1] = av.y;
            As[k][m0 + 2] = av.z; As[k][m0 + 3] = av.w;
        } else {
            const int m  = tid >> 2;          // 0..63
            const int k0 = (tid & 3) * 4;     // 0..12
            const float4 av = *(const float4*)&A[(size_t)(row0 + m) * Kd + kt + k0];
            As[k0 + 0][m] = av.x; As[k0 + 1][m] = av.y;
            As[k0 + 2][m] = av.z; As[k0 + 3][m] = av.w;
        }
        // ---- stage B tile: Bs[k][j] = B[col0+j][kt+k]
        {
            const int j  = tid >> 2;          // 0..63
            const int k0 = (tid & 3) * 4;
            const float4 bv = *(const float4*)&B[(size_t)(col0 + j) * Kd + kt + k0];
            Bs[k0 + 0][j] = bv.x; Bs[k0 + 1][j] = bv.y;
            Bs[k0 + 2][j] = bv.z; Bs[k0 + 3][j] = bv.w;
        }
        __syncthreads();
        #pragma unroll
        for (int k = 0; k < 16; ++k) {
            const float4 a = *(const float4*)&As[k][ty * 4];
            const float4 b = *(const float4*)&Bs[k][tx * 4];
            const float av[4] = {a.x, a.y, a.z, a.w};
            const float bv[4] = {b.x, b.y, b.z, b.w};
            #pragma unroll
            for (int i = 0; i < 4; ++i)
                #pragma unroll
                for (int j = 0; j < 4; ++j)
                    acc[i][j] += av[i] * bv[j];
        }
        __syncthreads();
    }

    const int m_base = row0 + ty * 4;
    const int n_base = col0 + tx * 4;
    #pragma unroll
    for (int i = 0; i < 4; ++i) {
        float4 r;
        #pragma unroll
        for (int j = 0; j < 4; ++j) {
            float v = acc[i][j] + bias[n_base + j];
            if (GELU) {
                // jax.nn.gelu approximate=True (tanh form)
                v = 0.5f * v * (1.0f + tanhf(0.7978845608028654f *
                        (v + 0.044715f * v * v * v)));
            }
            if (RES) v += res[(size_t)(m_base + i) * Nout + n_base + j];
            (&r.x)[j] = v;
        }
        *(float4*)&out[(size_t)(m_base + i) * Nout + n_base] = r;
    }
}

// ---------------------------------------------------------------------------
// Neighborhood attention: one block per spatial position, 128 thr = 8h x 16d
// qkv: (N, 384) rows [q(128) | k(128) | v(128)], rpb: (8,5,5,5)
// out: (N, 128) head-major
// ---------------------------------------------------------------------------
__global__ __launch_bounds__(128) void attn_kernel(
    const float* __restrict__ qkv, const float* __restrict__ rpb,
    float* __restrict__ out)
{
    const int n = blockIdx.x;
    const int t = threadIdx.x;
    __shared__ float qs[128];
    __shared__ float logits[NHEADS][27];
    __shared__ int nbr_s[27];
    __shared__ int bidx_s[27];

    const int pz = n & 31, pw = (n >> 5) & 31, ph = n >> 10;

    qs[t] = qkv[(size_t)n * C3 + t];
    if (t < 27) {
        const int ih = t / 9, iw = (t / 3) % 3, iz = t % 3;
        const int sh = min(max(ph - 1, 0), 29);
        const int sw = min(max(pw - 1, 0), 29);
        const int sz = min(max(pz - 1, 0), 29);
        const int nh = sh + ih, nw = sw + iw, nz = sz + iz;
        nbr_s[t] = (nh << 10) + (nw << 5) + nz;
        bidx_s[t] = ((nh - ph + 2) * 5 + (nw - pw + 2)) * 5 + (nz - pz + 2);
    }
    __syncthreads();

    const int h = t >> 4, j = t & 15;
    const float scale = 0.25f;  // hd^-0.5, hd=16
    for (int kk = j; kk < 27; kk += 16) {
        const float* krow = qkv + (size_t)nbr_s[kk] * C3 + CCH + h * HD;
        float a = 0.f;
        #pragma unroll
        for (int d = 0; d < HD; ++d) a += qs[h * HD + d] * krow[d];
        logits[h][kk] = a * scale + rpb[h * 125 + bidx_s[kk]];
    }
    __syncthreads();

    if (t < NHEADS) {
        float mx = -1e30f;
        for (int kk = 0; kk < 27; ++kk) mx = fmaxf(mx, logits[t][kk]);
        float s = 0.f;
        for (int kk = 0; kk < 27; ++kk) {
            const float e = __expf(logits[t][kk] - mx);
            logits[t][kk] = e; s += e;
        }
        const float inv = 1.f / s;
        for (int kk = 0; kk < 27; ++kk) logits[t][kk] *= inv;
    }
    __syncthreads();

    float a = 0.f;
    for (int kk = 0; kk < 27; ++kk)
        a += logits[h][kk] * qkv[(size_t)nbr_s[kk] * C3 + 2 * CCH + t];
    out[(size_t)n * CCH + t] = a;
}

// ---------------------------------------------------------------------------
// Channel stats (sum, sumsq) over N rows of an (N,128) tensor, via atomics.
// grid 256 x 128 threads; each block covers 128 rows.
// ---------------------------------------------------------------------------
__global__ __launch_bounds__(128) void stats_kernel(
    const float* __restrict__ a, float* __restrict__ stats)
{
    const int c = threadIdx.x;
    const int r0 = blockIdx.x * 128;
    float s = 0.f, sq = 0.f;
    for (int r = 0; r < 128; ++r) {
        const float v = a[(size_t)(r0 + r) * CCH + c];
        s += v; sq += v * v;
    }
    atomicAdd(&stats[c], s);
    atomicAdd(&stats[CCH + c], sq);
}

__global__ __launch_bounds__(256) void zero_kernel(float* __restrict__ p, int n)
{
    const int i = blockIdx.x * 256 + threadIdx.x;
    if (i < n) p[i] = 0.f;
}

// in-place instance-norm apply on (N,128), float4 over 4 consecutive channels
__global__ __launch_bounds__(256) void norm_apply_kernel(
    float* __restrict__ a, const float* __restrict__ stats)
{
    const int i = blockIdx.x * 256 + threadIdx.x;   // float4 index
    const int c0 = (i * 4) & (CCH - 1);
    float4 v = ((float4*)a)[i];
    const float invN = 1.f / (float)NPOS;
    #pragma unroll
    for (int j = 0; j < 4; ++j) {
        const int c = c0 + j;
        const float m = stats[c] * invN;
        const float var = stats[CCH + c] * invN - m * m;
        const float rs = rsqrtf(var + 1e-5f);
        (&v.x)[j] = ((&v.x)[j] - m) * rs;
    }
    ((float4*)a)[i] = v;
}

// normalize + transpose (N,C) -> (C,N) into d_out
__global__ __launch_bounds__(256) void norm_transpose_kernel(
    const float* __restrict__ t, const float* __restrict__ stats,
    float* __restrict__ out)
{
    __shared__ float tile[32][33];
    const int n0 = blockIdx.x * 32;
    const int c0 = blockIdx.y * 32;
    const int tx = threadIdx.x;         // 0..31
    const int ty = threadIdx.y;         // 0..7
    for (int i = ty; i < 32; i += 8)
        tile[i][tx] = t[(size_t)(n0 + i) * CCH + c0 + tx];
    __syncthreads();
    const float invN = 1.f / (float)NPOS;
    for (int i = ty; i < 32; i += 8) {
        const int c = c0 + i;
        const float m = stats[c] * invN;
        const float var = stats[CCH + c] * invN - m * m;
        const float rs = rsqrtf(var + 1e-5f);
        out[(size_t)c * NPOS + n0 + tx] = (tile[tx][i] - m) * rs;
    }
}

// ---------------------------------------------------------------------------
extern "C" void kernel_launch(void* const* d_in, const int* in_sizes, int n_in,
                              void* d_out, int out_size, void* d_ws, size_t ws_size,
                              hipStream_t stream)
{
    const float* x      = (const float*)d_in[0];   // (128, 32768) i.e. (C, N)
    const float* w_qkv  = (const float*)d_in[1];   // (384, 128)
    const float* b_qkv  = (const float*)d_in[2];   // (384)
    const float* rpb    = (const float*)d_in[3];   // (8,5,5,5)
    const float* w_proj = (const float*)d_in[4];   // (128, 128)
    const float* b_proj = (const float*)d_in[5];
    const float* w_ffn1 = (const float*)d_in[6];   // (512, 128)
    const float* b_ffn1 = (const float*)d_in[7];
    const float* w_ffn2 = (const float*)d_in[8];   // (128, 512)
    const float* b_ffn2 = (const float*)d_in[9];
    float* out = (float*)d_out;

    char* ws = (char*)d_ws;
    float* qkv   = (float*)(ws);                          // N*384 = 50.33 MB
    float* attnO = (float*)(ws + (size_t)50331648);       // N*128 = 16.78 MB
    float* x5    = (float*)(ws + (size_t)67108864);       // N*128
    float* ffn1  = (float*)(ws);                          // N*512, reuses qkv+attnO
    float* tbuf  = (float*)(ws + (size_t)83886080);       // N*128
    float* stats = (float*)(ws + (size_t)100663296);      // 2 x 256 floats

    float* stats1 = stats;        // proj-out norm
    float* stats2 = stats + 256;  // final norm

    // 0) zero stats
    zero_kernel<<<2, 256, 0, stream>>>(stats, 512);

    // 1) qkv = x^T @ w_qkv^T + b_qkv     (ATRANS: A stored (K=128, M=32768))
    gemm_kernel<true, false, false><<<dim3(C3 / 64, NPOS / 64), 256, 0, stream>>>(
        x, w_qkv, b_qkv, nullptr, qkv, NPOS, C3, CCH);

    // 2) neighborhood attention
    attn_kernel<<<NPOS, 128, 0, stream>>>(qkv, rpb, attnO);

    // 3) proj: x5 = attnO @ w_proj^T + b_proj
    gemm_kernel<false, false, false><<<dim3(CCH / 64, NPOS / 64), 256, 0, stream>>>(
        attnO, w_proj, b_proj, nullptr, x5, NPOS, CCH, CCH);

    // 4) instance norm #1 (in place on x5)
    stats_kernel<<<256, 128, 0, stream>>>(x5, stats1);
    norm_apply_kernel<<<(NPOS * CCH / 4) / 256, 256, 0, stream>>>(x5, stats1);

    // 5) ffn1 = gelu(x5 @ w_ffn1^T + b_ffn1)
    gemm_kernel<false, true, false><<<dim3(CF / 64, NPOS / 64), 256, 0, stream>>>(
        x5, w_ffn1, b_ffn1, nullptr, ffn1, NPOS, CF, CCH);

    // 6) t = x5 + ffn1 @ w_ffn2^T + b_ffn2
    gemm_kernel<false, false, true><<<dim3(CCH / 64, NPOS / 64), 256, 0, stream>>>(
        ffn1, w_ffn2, b_ffn2, x5, tbuf, NPOS, CCH, CF);

    // 7) instance norm #2 + transpose to (C, N) output
    stats_kernel<<<256, 128, 0, stream>>>(tbuf, stats2);
    norm_transpose_kernel<<<dim3(NPOS / 32, CCH / 32), dim3(32, 8), 0, stream>>>(
        tbuf, stats2, out);
}

// Round 2
// 233.700 us; speedup vs baseline: 1.6427x; 1.6427x over previous
//
#include <hip/hip_runtime.h>
#include <hip/hip_bf16.h>
#include <math.h>

#define NPOS 32768      // 32*32*32
#define CCH  128
#define C3   384
#define CF   512

typedef __attribute__((ext_vector_type(8))) short short8;
typedef __attribute__((ext_vector_type(4))) float f32x4;

__device__ inline float bf2f(unsigned short u) {
    union { unsigned int i; float f; } x; x.i = ((unsigned int)u) << 16; return x.f;
}
__device__ inline unsigned short f2bf(float f) {
    union { float f; unsigned int i; } x; x.f = f;
    unsigned int r = x.i + 0x7FFFu + ((x.i >> 16) & 1u);   // round-nearest-even
    return (unsigned short)(r >> 16);
}

// ---------------------------------------------------------------------------
// bf16 MFMA GEMM: out[M,Nout] = A(M,K) * B(Nout,K)^T + bias (+gelu)(+residual)
// 128x128 tile, BK=32, 256 thr = 4 waves (2x2 of 64x64), 16x16x32 bf16 MFMA.
// Writes fp32 and/or bf16 output per template flags.
// ---------------------------------------------------------------------------
template<bool GELU, bool RES, bool WF32, bool WBF>
__global__ __launch_bounds__(256) void gemm_mfma(
    const unsigned short* __restrict__ A, const unsigned short* __restrict__ B,
    const float* __restrict__ bias, const unsigned short* __restrict__ res,
    float* __restrict__ outf, unsigned short* __restrict__ outb,
    int M, int Nout, int K)
{
    // rows padded to 40 shorts (80 B): keeps 16B alignment, spreads banks
    __shared__ alignas(16) unsigned short As[128 * 40];
    __shared__ alignas(16) unsigned short Bs[128 * 40];

    const int tid  = threadIdx.x;
    const int lane = tid & 63;
    const int wave = tid >> 6;
    const int wm = wave & 1, wn = wave >> 1;
    const int row0 = blockIdx.y * 128;
    const int col0 = blockIdx.x * 128;

    const f32x4 fzero = {0.f, 0.f, 0.f, 0.f};
    f32x4 acc[4][4];
    #pragma unroll
    for (int i = 0; i < 4; ++i)
        #pragma unroll
        for (int j = 0; j < 4; ++j) acc[i][j] = fzero;

    const int lr = lane & 15;           // m (A) / n (B) within 16-subtile
    const int lk = (lane >> 4) * 8;     // k offset in shorts

    for (int kt = 0; kt < K; kt += 32) {
        #pragma unroll
        for (int it = 0; it < 2; ++it) {
            const int c = tid + it * 256;        // 0..511 chunk of 16B
            const int r = c >> 2;                // row 0..127
            const int p = (c & 3) * 8;           // col offset in shorts
            *(uint4*)&As[r * 40 + p] = *(const uint4*)&A[(size_t)(row0 + r) * K + kt + p];
            *(uint4*)&Bs[r * 40 + p] = *(const uint4*)&B[(size_t)(col0 + r) * K + kt + p];
        }
        __syncthreads();
        short8 af[4], bfr[4];
        #pragma unroll
        for (int i = 0; i < 4; ++i)
            af[i]  = *(const short8*)&As[(wm * 64 + i * 16 + lr) * 40 + lk];
        #pragma unroll
        for (int j = 0; j < 4; ++j)
            bfr[j] = *(const short8*)&Bs[(wn * 64 + j * 16 + lr) * 40 + lk];
        #pragma unroll
        for (int i = 0; i < 4; ++i)
            #pragma unroll
            for (int j = 0; j < 4; ++j)
                acc[i][j] = __builtin_amdgcn_mfma_f32_16x16x32_bf16(
                                af[i], bfr[j], acc[i][j], 0, 0, 0);
        __syncthreads();
    }

    // C/D layout: col = lane&15, row = (lane>>4)*4 + reg
    const int gr0 = row0 + wm * 64 + (lane >> 4) * 4;
    const int gc0 = col0 + wn * 64 + lr;
    #pragma unroll
    for (int j = 0; j < 4; ++j) {
        const int gc = gc0 + j * 16;
        const float bv = bias[gc];
        #pragma unroll
        for (int i = 0; i < 4; ++i) {
            #pragma unroll
            for (int r = 0; r < 4; ++r) {
                const int gr = gr0 + i * 16 + r;
                float v = acc[i][j][r] + bv;
                if (GELU) {
                    const float g = 0.7978845608028654f * (v + 0.044715f * v * v * v);
                    const float e = __expf(2.f * g);
                    v = v * (e / (e + 1.f));     // == 0.5*v*(1+tanh(g))
                }
                if (RES)  v += bf2f(res[(size_t)gr * Nout + gc]);
                if (WF32) outf[(size_t)gr * Nout + gc] = v;
                if (WBF)  outb[(size_t)gr * Nout + gc] = f2bf(v);
            }
        }
    }
}

// ---------------------------------------------------------------------------
// Neighborhood attention on bf16 qkv (N,384 = q|k|v), out bf16 (N,128)
// ---------------------------------------------------------------------------
__global__ __launch_bounds__(128) void attn_kernel(
    const unsigned short* __restrict__ qkv, const float* __restrict__ rpb,
    unsigned short* __restrict__ out)
{
    const int n = blockIdx.x;
    const int t = threadIdx.x;
    __shared__ float qs[128];
    __shared__ float logits[8][27];
    __shared__ int nbr_s[27];
    __shared__ int bidx_s[27];

    const int pz = n & 31, pw = (n >> 5) & 31, ph = n >> 10;

    qs[t] = bf2f(qkv[(size_t)n * C3 + t]);
    if (t < 27) {
        const int ih = t / 9, iw = (t / 3) % 3, iz = t % 3;
        const int sh = min(max(ph - 1, 0), 29);
        const int sw = min(max(pw - 1, 0), 29);
        const int sz = min(max(pz - 1, 0), 29);
        const int nh = sh + ih, nw = sw + iw, nz = sz + iz;
        nbr_s[t] = (nh << 10) + (nw << 5) + nz;
        bidx_s[t] = ((nh - ph + 2) * 5 + (nw - pw + 2)) * 5 + (nz - pz + 2);
    }
    __syncthreads();

    const int h = t >> 4, j = t & 15;
    for (int kk = j; kk < 27; kk += 16) {
        const uint4* kp = (const uint4*)&qkv[(size_t)nbr_s[kk] * C3 + CCH + h * 16];
        const uint4 k0 = kp[0], k1 = kp[1];
        const unsigned short* kv0 = (const unsigned short*)&k0;
        const unsigned short* kv1 = (const unsigned short*)&k1;
        float a = 0.f;
        #pragma unroll
        for (int d = 0; d < 8; ++d) a += qs[h * 16 + d] * bf2f(kv0[d]);
        #pragma unroll
        for (int d = 0; d < 8; ++d) a += qs[h * 16 + 8 + d] * bf2f(kv1[d]);
        logits[h][kk] = a * 0.25f + rpb[h * 125 + bidx_s[kk]];
    }
    __syncthreads();

    if (t < 8) {
        float mx = -1e30f;
        for (int kk = 0; kk < 27; ++kk) mx = fmaxf(mx, logits[t][kk]);
        float s = 0.f;
        for (int kk = 0; kk < 27; ++kk) {
            const float e = __expf(logits[t][kk] - mx);
            logits[t][kk] = e; s += e;
        }
        const float inv = 1.f / s;
        for (int kk = 0; kk < 27; ++kk) logits[t][kk] *= inv;
    }
    __syncthreads();

    float a = 0.f;
    for (int kk = 0; kk < 27; ++kk)
        a += logits[h][kk] * bf2f(qkv[(size_t)nbr_s[kk] * C3 + 2 * CCH + t]);
    out[(size_t)n * CCH + t] = f2bf(a);
}

// ---------------------------------------------------------------------------
// helpers: stats / norm / transpose / convert
// ---------------------------------------------------------------------------
__global__ __launch_bounds__(128) void stats_kernel(
    const float* __restrict__ a, float* __restrict__ stats)
{
    const int c = threadIdx.x;
    const int r0 = blockIdx.x * 128;
    float s = 0.f, sq = 0.f;
    for (int r = 0; r < 128; ++r) {
        const float v = a[(size_t)(r0 + r) * CCH + c];
        s += v; sq += v * v;
    }
    atomicAdd(&stats[c], s);
    atomicAdd(&stats[CCH + c], sq);
}

__global__ __launch_bounds__(256) void zero_kernel(float* __restrict__ p, int n)
{
    const int i = blockIdx.x * 256 + threadIdx.x;
    if (i < n) p[i] = 0.f;
}

// normalize (N,128) fp32 -> bf16
__global__ __launch_bounds__(256) void norm_apply_bf(
    const float* __restrict__ a, const float* __restrict__ stats,
    unsigned short* __restrict__ o)
{
    const int i = blockIdx.x * 256 + threadIdx.x;   // float4 index
    const int c0 = (i * 4) & (CCH - 1);
    const float4 v = ((const float4*)a)[i];
    const float invN = 1.f / (float)NPOS;
    ushort4 r;
    #pragma unroll
    for (int j = 0; j < 4; ++j) {
        const int c = c0 + j;
        const float m = stats[c] * invN;
        const float var = stats[CCH + c] * invN - m * m;
        const float rs = rsqrtf(var + 1e-5f);
        (&r.x)[j] = f2bf(((&v.x)[j] - m) * rs);
    }
    *(ushort4*)&o[(size_t)i * 4] = r;
}

// normalize + transpose (N,C) fp32 -> (C,N) fp32 output
__global__ void norm_transpose_kernel(
    const float* __restrict__ t, const float* __restrict__ stats,
    float* __restrict__ out)
{
    __shared__ float tile[32][33];
    const int n0 = blockIdx.x * 32;
    const int c0 = blockIdx.y * 32;
    const int tx = threadIdx.x;         // 0..31
    const int ty = threadIdx.y;         // 0..7
    for (int i = ty; i < 32; i += 8)
        tile[i][tx] = t[(size_t)(n0 + i) * CCH + c0 + tx];
    __syncthreads();
    const float invN = 1.f / (float)NPOS;
    for (int i = ty; i < 32; i += 8) {
        const int c = c0 + i;
        const float m = stats[c] * invN;
        const float var = stats[CCH + c] * invN - m * m;
        const float rs = rsqrtf(var + 1e-5f);
        out[(size_t)c * NPOS + n0 + tx] = (tile[tx][i] - m) * rs;
    }
}

// transpose x (C,N) fp32 -> (N,C) bf16
__global__ __launch_bounds__(256) void transpose_x_kernel(
    const float* __restrict__ x, unsigned short* __restrict__ xt)
{
    __shared__ float tile[32][33];
    const int n0 = blockIdx.x * 32;
    const int c0 = blockIdx.y * 32;
    const int tx = threadIdx.x & 31;
    const int ty = threadIdx.x >> 5;    // 0..7
    for (int i = ty; i < 32; i += 8)
        tile[i][tx] = x[(size_t)(c0 + i) * NPOS + n0 + tx];
    __syncthreads();
    for (int i = ty; i < 32; i += 8)
        xt[(size_t)(n0 + i) * CCH + c0 + tx] = f2bf(tile[tx][i]);
}

// fp32 -> bf16 (vectorized by 4)
__global__ __launch_bounds__(256) void f2bf_kernel(
    const float* __restrict__ src, unsigned short* __restrict__ dst, int n4)
{
    const int i = blockIdx.x * 256 + threadIdx.x;
    if (i < n4) {
        const float4 v = ((const float4*)src)[i];
        ushort4 o;
        o.x = f2bf(v.x); o.y = f2bf(v.y); o.z = f2bf(v.z); o.w = f2bf(v.w);
        ((ushort4*)dst)[i] = o;
    }
}

// ---------------------------------------------------------------------------
extern "C" void kernel_launch(void* const* d_in, const int* in_sizes, int n_in,
                              void* d_out, int out_size, void* d_ws, size_t ws_size,
                              hipStream_t stream)
{
    const float* x      = (const float*)d_in[0];   // (128, 32768) = (C, N)
    const float* w_qkv  = (const float*)d_in[1];   // (384, 128)
    const float* b_qkv  = (const float*)d_in[2];
    const float* rpb    = (const float*)d_in[3];   // (8,5,5,5)
    const float* w_proj = (const float*)d_in[4];   // (128, 128)
    const float* b_proj = (const float*)d_in[5];
    const float* w_ffn1 = (const float*)d_in[6];   // (512, 128)
    const float* b_ffn1 = (const float*)d_in[7];
    const float* w_ffn2 = (const float*)d_in[8];   // (128, 512)
    const float* b_ffn2 = (const float*)d_in[9];
    float* out = (float*)d_out;

    char* ws = (char*)d_ws;
    unsigned short* xt_bf    = (unsigned short*)(ws + 0);          // 8.39 MB
    unsigned short* qkv_bf   = (unsigned short*)(ws + 8388608);    // 25.2 MB -> 33,554,432
    unsigned short* ffn1_bf  = (unsigned short*)(ws + 0);          // 33.6 MB (reuses xt+qkv)
    unsigned short* attnO_bf = (unsigned short*)(ws + 33554432);   // 8.39 MB -> 41,943,040
    float*          x5       = (float*)(ws + 41943040);            // 16.8 MB -> 58,720,256
    unsigned short* x5n_bf   = (unsigned short*)(ws + 58720256);   // 8.39 MB -> 67,108,864
    float*          tbuf     = (float*)(ws + 67108864);            // 16.8 MB -> 83,886,080
    unsigned short* wqkv_bf  = (unsigned short*)(ws + 83886080);   // 96 KB
    unsigned short* wproj_bf = (unsigned short*)(ws + 83984384);   // 32 KB
    unsigned short* wffn1_bf = (unsigned short*)(ws + 84017152);   // 128 KB
    unsigned short* wffn2_bf = (unsigned short*)(ws + 84148224);   // 128 KB
    float*          stats    = (float*)(ws + 84279296);            // 512 floats

    // 0) zero both stats blocks; convert weights; transpose-convert x
    zero_kernel<<<2, 256, 0, stream>>>(stats, 512);
    f2bf_kernel<<<48, 256, 0, stream>>>(w_qkv,  wqkv_bf,  12288);
    f2bf_kernel<<<16, 256, 0, stream>>>(w_proj, wproj_bf, 4096);
    f2bf_kernel<<<64, 256, 0, stream>>>(w_ffn1, wffn1_bf, 16384);
    f2bf_kernel<<<64, 256, 0, stream>>>(w_ffn2, wffn2_bf, 16384);
    transpose_x_kernel<<<dim3(NPOS / 32, CCH / 32), 256, 0, stream>>>(x, xt_bf);

    // 1) qkv = xt @ w_qkv^T + b_qkv   (bf16 out)
    gemm_mfma<false, false, false, true><<<dim3(C3 / 128, NPOS / 128), 256, 0, stream>>>(
        xt_bf, wqkv_bf, b_qkv, nullptr, nullptr, qkv_bf, NPOS, C3, CCH);

    // 2) neighborhood attention (bf16 in/out)
    attn_kernel<<<NPOS, 128, 0, stream>>>(qkv_bf, rpb, attnO_bf);

    // 3) x5 = attnO @ w_proj^T + b_proj  (fp32 out)
    gemm_mfma<false, false, true, false><<<dim3(1, NPOS / 128), 256, 0, stream>>>(
        attnO_bf, wproj_bf, b_proj, nullptr, x5, nullptr, NPOS, CCH, CCH);

    // 4) instance norm #1: fp32 stats, bf16 normalized output
    stats_kernel<<<256, 128, 0, stream>>>(x5, stats);
    norm_apply_bf<<<(NPOS * CCH / 4) / 256, 256, 0, stream>>>(x5, stats, x5n_bf);

    // 5) ffn1 = gelu(x5n @ w_ffn1^T + b_ffn1)  (bf16 out)
    gemm_mfma<true, false, false, true><<<dim3(CF / 128, NPOS / 128), 256, 0, stream>>>(
        x5n_bf, wffn1_bf, b_ffn1, nullptr, nullptr, ffn1_bf, NPOS, CF, CCH);

    // 6) t = x5n + ffn1 @ w_ffn2^T + b_ffn2  (fp32 out)
    gemm_mfma<false, true, true, false><<<dim3(1, NPOS / 128), 256, 0, stream>>>(
        ffn1_bf, wffn2_bf, b_ffn2, x5n_bf, tbuf, nullptr, NPOS, CCH, CF);

    // 7) instance norm #2 + transpose to (C,N)
    stats_kernel<<<256, 128, 0, stream>>>(tbuf, stats + 256);
    norm_transpose_kernel<<<dim3(NPOS / 32, CCH / 32), dim3(32, 8), 0, stream>>>(
        tbuf, stats + 256, out);
}